// Round 1
// baseline (84.052 us; speedup 1.0000x reference)
//
#include <hip/hip_runtime.h>

// ExodusNet: weighted = W[1,32] @ x[B,32,T]  ->  LIF scan over T -> spikes [B,1,T]
// B = 32768, F = 32 (C*H*W), T = 100. All float32.
//
// Memory-bound: x = 419 MB read, out = 13 MB write. Strategy:
//   Phase 1: per-block, compute weighted[64 b][100 t] with float4 loads over T
//            (coalesced; every x element read exactly once), stage in LDS.
//   Phase 2: 1 thread per batch element runs the sequential 100-step LIF scan
//            in LDS (XOR-swizzled float4 rows -> bank-conflict-free).
//   Phase 3: coalesced float4 stores of the spike outputs.

#define NB     64      // batch elements per block
#define BLOCK  256     // threads per block
#define TT     100     // time steps
#define FF     32      // features
#define T4     (TT/4)  // 25 float4 groups per row
#define ROWPAD 128     // dwords per LDS row (32 float4 slots: t4^ (bl&7) fits)

__global__ __launch_bounds__(BLOCK) void exodus_lif_kernel(
        const float* __restrict__ x,
        const float* __restrict__ Wg,
        float* __restrict__ out)
{
    __shared__ __align__(16) float wbuf[NB * ROWPAD];  // 32 KB
    __shared__ float sW[FF];

    const int  tid = threadIdx.x;
    const long b0  = (long)blockIdx.x * NB;

    if (tid < FF) sW[tid] = Wg[tid];
    __syncthreads();

    // ---- Phase 1: weighted[bl][t] = sum_f W[f] * x[b0+bl, f, t] ----
    const int NITEM = NB * T4;  // 1600
    for (int item = tid; item < NITEM; item += BLOCK) {
        const int bl = item / T4;
        const int t4 = item % T4;
        const float4* xp =
            reinterpret_cast<const float4*>(x + (b0 + bl) * (long)(FF * TT) + t4 * 4);
        float4 acc = make_float4(0.f, 0.f, 0.f, 0.f);
#pragma unroll
        for (int f = 0; f < FF; ++f) {
            const float4 xv = xp[f * T4];
            const float  w  = sW[f];
            acc.x += w * xv.x;
            acc.y += w * xv.y;
            acc.z += w * xv.z;
            acc.w += w * xv.w;
        }
        const int t4s = t4 ^ (bl & 7);  // bank swizzle
        *reinterpret_cast<float4*>(&wbuf[bl * ROWPAD + t4s * 4]) = acc;
    }
    __syncthreads();

    // ---- Phase 2: sequential LIF scan, one thread per batch element ----
    if (tid < NB) {
        const float A  = 0.90483741803595952f;  // exp(-1/10)
        const float OM = 0.09516258196404048f;  // 1 - A
        const int   bl = tid;
        float v = 0.f;
#pragma unroll
        for (int t4 = 0; t4 < T4; ++t4) {
            const int t4s = t4 ^ (bl & 7);
            float4 w = *reinterpret_cast<float4*>(&wbuf[bl * ROWPAD + t4s * 4]);
            float* we = &w.x;
#pragma unroll
            for (int k = 0; k < 4; ++k) {
                v = A * v + OM * we[k];
                const float s = (v >= 1.0f) ? 1.0f : 0.0f;
                v -= s;
                we[k] = s;
            }
            *reinterpret_cast<float4*>(&wbuf[bl * ROWPAD + t4s * 4]) = w;
        }
    }
    __syncthreads();

    // ---- Phase 3: coalesced spike writeback ----
    for (int item = tid; item < NITEM; item += BLOCK) {
        const int bl  = item / T4;
        const int t4  = item % T4;
        const int t4s = t4 ^ (bl & 7);
        const float4 s = *reinterpret_cast<const float4*>(&wbuf[bl * ROWPAD + t4s * 4]);
        *reinterpret_cast<float4*>(out + (b0 + bl) * (long)TT + t4 * 4) = s;
    }
}

extern "C" void kernel_launch(void* const* d_in, const int* in_sizes, int n_in,
                              void* d_out, int out_size, void* d_ws, size_t ws_size,
                              hipStream_t stream) {
    const float* x  = (const float*)d_in[0];   // [32768, 2, 4, 4, 100] = [B, 32, 100]
    const float* Wg = (const float*)d_in[1];   // [1, 32]
    float* out      = (float*)d_out;           // [32768, 1, 100]

    const int B    = in_sizes[0] / (FF * TT);  // 32768
    const int grid = B / NB;                   // 512

    exodus_lif_kernel<<<grid, BLOCK, 0, stream>>>(x, Wg, out);
}

// Round 3
// 83.624 us; speedup vs baseline: 1.0051x; 1.0051x over previous
//
#include <hip/hip_runtime.h>

// ExodusNet: weighted = W[1,32] @ x[B,32,T]  ->  LIF scan over T -> spikes [B,1,T]
// B = 32768, F = 32 (C*H*W), T = 100. All float32.
//
// Memory-bound: x = 419 MB read, out = 13 MB write. Strategy:
//   Phase 1: per-block, compute weighted[32 b][100 t] with float4 loads over T
//            (coalesced; every x element read exactly once), stage in LDS.
//   Phase 2: 1 thread per batch element runs the sequential 100-step LIF scan
//            in LDS (XOR-swizzled float4 rows -> bank-conflict-free).
//   Phase 3: coalesced float4 stores of the spike outputs.
//
// R2: NB 64->32 (grid 512->1024, 4 blocks/CU resident) so barrier/scan stalls
//     of one block are hidden by three other streaming blocks; W read directly
//     from global (uniform address -> s_load broadcast), drops a barrier.
// R3: identical resubmit (R2 bench died to an unresponsive container).

#define NB     32      // batch elements per block
#define BLOCK  256     // threads per block
#define TT     100     // time steps
#define FF     32      // features
#define T4     (TT/4)  // 25 float4 groups per row
#define ROWPAD 128     // dwords per LDS row (32 float4 slots: t4 ^ (bl&7) fits)

__global__ __launch_bounds__(BLOCK) void exodus_lif_kernel(
        const float* __restrict__ x,
        const float* __restrict__ Wg,
        float* __restrict__ out)
{
    __shared__ __align__(16) float wbuf[NB * ROWPAD];  // 16 KB

    const int  tid = threadIdx.x;
    const long b0  = (long)blockIdx.x * NB;

    // ---- Phase 1: weighted[bl][t] = sum_f W[f] * x[b0+bl, f, t] ----
    const int NITEM = NB * T4;  // 800
    for (int item = tid; item < NITEM; item += BLOCK) {
        const int bl = item / T4;
        const int t4 = item % T4;
        const float4* xp =
            reinterpret_cast<const float4*>(x + (b0 + bl) * (long)(FF * TT) + t4 * 4);
        float4 acc = make_float4(0.f, 0.f, 0.f, 0.f);
#pragma unroll
        for (int f = 0; f < FF; ++f) {
            const float4 xv = xp[f * T4];
            const float  w  = Wg[f];   // uniform address -> scalar load broadcast
            acc.x += w * xv.x;
            acc.y += w * xv.y;
            acc.z += w * xv.z;
            acc.w += w * xv.w;
        }
        const int t4s = t4 ^ (bl & 7);  // bank swizzle
        *reinterpret_cast<float4*>(&wbuf[bl * ROWPAD + t4s * 4]) = acc;
    }
    __syncthreads();

    // ---- Phase 2: sequential LIF scan, one thread per batch element ----
    if (tid < NB) {
        const float A  = 0.90483741803595952f;  // exp(-1/10)
        const float OM = 0.09516258196404048f;  // 1 - A
        const int   bl = tid;
        float v = 0.f;
#pragma unroll
        for (int t4 = 0; t4 < T4; ++t4) {
            const int t4s = t4 ^ (bl & 7);
            float4 w = *reinterpret_cast<float4*>(&wbuf[bl * ROWPAD + t4s * 4]);
            float* we = &w.x;
#pragma unroll
            for (int k = 0; k < 4; ++k) {
                v = A * v + OM * we[k];
                const float s = (v >= 1.0f) ? 1.0f : 0.0f;
                v -= s;
                we[k] = s;
            }
            *reinterpret_cast<float4*>(&wbuf[bl * ROWPAD + t4s * 4]) = w;
        }
    }
    __syncthreads();

    // ---- Phase 3: coalesced spike writeback ----
    for (int item = tid; item < NITEM; item += BLOCK) {
        const int bl  = item / T4;
        const int t4  = item % T4;
        const int t4s = t4 ^ (bl & 7);
        const float4 s = *reinterpret_cast<const float4*>(&wbuf[bl * ROWPAD + t4s * 4]);
        *reinterpret_cast<float4*>(out + (b0 + bl) * (long)TT + t4 * 4) = s;
    }
}

extern "C" void kernel_launch(void* const* d_in, const int* in_sizes, int n_in,
                              void* d_out, int out_size, void* d_ws, size_t ws_size,
                              hipStream_t stream) {
    const float* x  = (const float*)d_in[0];   // [32768, 2, 4, 4, 100] = [B, 32, 100]
    const float* Wg = (const float*)d_in[1];   // [1, 32]
    float* out      = (float*)d_out;           // [32768, 1, 100]

    const int B    = in_sizes[0] / (FF * TT);  // 32768
    const int grid = B / NB;                   // 1024

    exodus_lif_kernel<<<grid, BLOCK, 0, stream>>>(x, Wg, out);
}